// Round 3
// baseline (183.989 us; speedup 1.0000x reference)
//
#include <hip/hip_runtime.h>
#include <hip/hip_bf16.h>
#include <cstdint>

typedef __bf16 bf16x8 __attribute__((ext_vector_type(8)));
typedef float  f32x16 __attribute__((ext_vector_type(16)));
typedef unsigned int uint2v __attribute__((ext_vector_type(2)));

#define B_ 4
#define S_ 2048
#define D_ 256
#define H_ 8
#define E_ 32

// d_model^-0.5 * log2(e) folded into Q so softmax uses exp2 directly
#define QSCALE (0.0625f * 1.44269504088896f)

__device__ inline unsigned short bfbits(float f) {
    return __builtin_bit_cast(unsigned short, (__bf16)f);
}
__device__ inline unsigned int pack2(float a, float b) {
    return (unsigned int)bfbits(a) | ((unsigned int)bfbits(b) << 16);
}

// ---------------------------------------------------------------------------
// Prep: wT[(op*8+h)*32+e][d] = w_op[h][d][e] (bf16, Q pre-scaled). 196608 elems.
// ---------------------------------------------------------------------------
__global__ __launch_bounds__(256) void prep_kernel(
    const float* __restrict__ wq, const float* __restrict__ wk,
    const float* __restrict__ wv, __bf16* __restrict__ wT)
{
    int idx = blockIdx.x * 256 + threadIdx.x;      // < 3*8*256*32 = 196608
    int op = idx >> 16;
    int h  = (idx >> 13) & 7;
    int d  = (idx >> 5) & 255;
    int e  = idx & 31;
    const float* w = (op == 0) ? wq : (op == 1) ? wk : wv;
    float v = w[(h * D_ + d) * E_ + e];
    if (op == 0) v *= QSCALE;
    wT[(((op * H_ + h) * E_ + e) << 8) | d] = (__bf16)v;
}

// ---------------------------------------------------------------------------
// QKV: x(8192x256 f32) @ wT^T -> Q,K [bh][S][E], V^T [bh][E][S]  (bf16)
// grid (256 row-tiles, 3 ops), 4 waves; each wave = 2 heads of its op.
// ---------------------------------------------------------------------------
__global__ __launch_bounds__(256, 2) void qkv_kernel(
    const float* __restrict__ x, const __bf16* __restrict__ wT,
    __bf16* __restrict__ Qb, __bf16* __restrict__ Kb, __bf16* __restrict__ VTb)
{
    const int tid = threadIdx.x;
    const int wid = tid >> 6, lane = tid & 63;
    const int c = lane & 31, hi = lane >> 5;
    const int row0 = blockIdx.x * 32;
    const int row = row0 + c;
    const int op = blockIdx.y;

    // A-fragments: step t covers d = 16t + 8*hi + (0..7)
    bf16x8 a[16];
    #pragma unroll
    for (int t = 0; t < 16; ++t) {
        const float4* px = reinterpret_cast<const float4*>(x + row * D_ + 16 * t + 8 * hi);
        float4 f0 = px[0], f1 = px[1];
        bf16x8 v;
        v[0]=(__bf16)f0.x; v[1]=(__bf16)f0.y; v[2]=(__bf16)f0.z; v[3]=(__bf16)f0.w;
        v[4]=(__bf16)f1.x; v[5]=(__bf16)f1.y; v[6]=(__bf16)f1.z; v[7]=(__bf16)f1.w;
        a[t] = v;
    }

    const int b  = row0 >> 11;
    const int s0 = row0 & (S_ - 1);

    for (int j = 0; j < 2; ++j) {
        const int h = wid * 2 + j;                 // head 0..7
        const int ct = op * 8 + h;
        const int col = ct * 32 + c;
        const __bf16* wp = wT + col * 256 + 8 * hi;

        f32x16 acc = {};
        #pragma unroll
        for (int t = 0; t < 16; ++t) {
            bf16x8 bb = *reinterpret_cast<const bf16x8*>(wp + 16 * t);
            acc = __builtin_amdgcn_mfma_f32_32x32x16_bf16(a[t], bb, acc, 0, 0, 0);
        }

        const int bh = b * H_ + h;
        if (op < 2) {
            __bf16* dst = (op == 0 ? Qb : Kb) + (size_t)bh * S_ * E_ + c;
            #pragma unroll
            for (int r = 0; r < 16; ++r) {
                int rr = (r & 3) + 8 * (r >> 2) + 4 * hi;
                dst[(size_t)(s0 + rr) * E_] = (__bf16)acc[r];
            }
        } else {
            __bf16* dst = VTb + ((size_t)bh * E_ + c) * S_ + s0;
            #pragma unroll
            for (int g4 = 0; g4 < 4; ++g4) {
                unsigned int lo  = pack2(acc[4*g4],   acc[4*g4+1]);
                unsigned int hi2 = pack2(acc[4*g4+2], acc[4*g4+3]);
                *reinterpret_cast<uint2*>(dst + 8 * g4 + 4 * hi) = make_uint2(lo, hi2);
            }
        }
    }
}

// ---------------------------------------------------------------------------
// Flash attention, 32x32 swapped form, block-level split-K.
// grid (64 qtiles, 32 bh), block 256 = 4 waves; block owns one 32-q tile,
// wave w handles k in [512w, 512w+512) with private online softmax, then
// the block combines partials through LDS.
// ---------------------------------------------------------------------------
__global__ __launch_bounds__(256, 8) void attn_kernel(
    const __bf16* __restrict__ Qb, const __bf16* __restrict__ Kb,
    const __bf16* __restrict__ VTb, __bf16* __restrict__ CTX)
{
    __shared__ float cacc[4][32][32];   // [wave][e][q] scaled partial ctx
    __shared__ float mls[2][4][32];     // m / lsum per wave per q

    const int tid = threadIdx.x;
    const int wid = tid >> 6, lane = tid & 63;
    const int c = lane & 31, hi = lane >> 5;
    const int bh = blockIdx.y;
    const int q0 = blockIdx.x * 32;
    const bool islo = (hi == 0);
    const int kbeg = wid * 512;

    const __bf16* Qh    = Qb + (size_t)bh * S_ * E_;
    const __bf16* kbase = Kb + (size_t)bh * S_ * E_ + c * E_ + 8 * hi;
    const __bf16* vbase = VTb + (size_t)bh * E_ * S_ + c * S_ + 8 * hi;

    const bf16x8 qb0 = *reinterpret_cast<const bf16x8*>(Qh + (q0 + c) * E_ + 8 * hi);
    const bf16x8 qb1 = *reinterpret_cast<const bf16x8*>(Qh + (q0 + c) * E_ + 16 + 8 * hi);

    f32x16 ctx = {};
    float m = -1e30f, lsum = 0.f;

    bf16x8 kA0, kA1, vA0, vA1, kB0, kB1, vB0, vB1;

#define LOADSET(K0, K1, V0, V1, kt) do { \
    K0 = *reinterpret_cast<const bf16x8*>(kbase + (size_t)(kt) * E_);      \
    K1 = *reinterpret_cast<const bf16x8*>(kbase + (size_t)(kt) * E_ + 16); \
    V0 = *reinterpret_cast<const bf16x8*>(vbase + (kt));                   \
    V1 = *reinterpret_cast<const bf16x8*>(vbase + (kt) + 16); } while (0)

    auto xpartner = [&](float v) -> float {
        uint2v r = __builtin_amdgcn_permlane32_swap(
            __builtin_bit_cast(unsigned int, v),
            __builtin_bit_cast(unsigned int, v), false, false);
        return __builtin_bit_cast(float, islo ? r[1] : r[0]);
    };

    auto compute = [&](const bf16x8& K0, const bf16x8& K1,
                       const bf16x8& V0, const bf16x8& V1) {
        f32x16 sc = {};
        sc = __builtin_amdgcn_mfma_f32_32x32x16_bf16(K0, qb0, sc, 0, 0, 0);
        sc = __builtin_amdgcn_mfma_f32_32x32x16_bf16(K1, qb1, sc, 0, 0, 0);

        // per-lane max tree (partner swap deferred to the rare branch:
        // __all already spans all 64 lanes)
        float t0 = fmaxf(fmaxf(sc[0], sc[1]),  fmaxf(sc[2], sc[3]));
        float t1 = fmaxf(fmaxf(sc[4], sc[5]),  fmaxf(sc[6], sc[7]));
        float t2 = fmaxf(fmaxf(sc[8], sc[9]),  fmaxf(sc[10], sc[11]));
        float t3 = fmaxf(fmaxf(sc[12], sc[13]), fmaxf(sc[14], sc[15]));
        float t = fmaxf(fmaxf(t0, t1), fmaxf(t2, t3));

        if (!__all(t <= m + 8.0f)) {          // rescale (≈once per wave)
            t = fmaxf(t, xpartner(t));
            float mnew = fmaxf(m, t);
            float f = __builtin_amdgcn_exp2f(m - mnew);
            lsum *= f;
            #pragma unroll
            for (int i = 0; i < 16; ++i) ctx[i] *= f;
            m = mnew;
        }

        float p[16];
        #pragma unroll
        for (int i = 0; i < 16; ++i) p[i] = __builtin_amdgcn_exp2f(sc[i] - m);
        float s0 = (p[0] + p[1]) + (p[2] + p[3]);
        float s1 = (p[4] + p[5]) + (p[6] + p[7]);
        float s2 = (p[8] + p[9]) + (p[10] + p[11]);
        float s3 = (p[12] + p[13]) + (p[14] + p[15]);
        float psum = (s0 + s1) + (s2 + s3);
        psum += xpartner(psum);
        lsum += psum;

        // PV B-frag, k-half 0 (k 0..15)
        unsigned int c0 = pack2(p[0], p[1]), c1 = pack2(p[2], p[3]);
        unsigned int c2 = pack2(p[4], p[5]), c3 = pack2(p[6], p[7]);
        uint2v r02 = __builtin_amdgcn_permlane32_swap(c0, c2, false, false);
        uint2v r13 = __builtin_amdgcn_permlane32_swap(c1, c3, false, false);
        uint4 u0; u0.x = r02[0]; u0.y = r13[0]; u0.z = r02[1]; u0.w = r13[1];
        // k-half 1 (k 16..31)
        c0 = pack2(p[8], p[9]);   c1 = pack2(p[10], p[11]);
        c2 = pack2(p[12], p[13]); c3 = pack2(p[14], p[15]);
        r02 = __builtin_amdgcn_permlane32_swap(c0, c2, false, false);
        r13 = __builtin_amdgcn_permlane32_swap(c1, c3, false, false);
        uint4 u1; u1.x = r02[0]; u1.y = r13[0]; u1.z = r02[1]; u1.w = r13[1];

        __builtin_amdgcn_s_setprio(1);
        ctx = __builtin_amdgcn_mfma_f32_32x32x16_bf16(V0, __builtin_bit_cast(bf16x8, u0), ctx, 0, 0, 0);
        ctx = __builtin_amdgcn_mfma_f32_32x32x16_bf16(V1, __builtin_bit_cast(bf16x8, u1), ctx, 0, 0, 0);
        __builtin_amdgcn_s_setprio(0);
    };

    LOADSET(kA0, kA1, vA0, vA1, kbeg);
    for (int kt = kbeg; kt < kbeg + 512; kt += 64) {
        LOADSET(kB0, kB1, vB0, vB1, kt + 32);
        compute(kA0, kA1, vA0, vA1);
        int ktn = (kt + 64 < kbeg + 512) ? kt + 64 : kbeg;  // stay in-bounds
        LOADSET(kA0, kA1, vA0, vA1, ktn);
        compute(kB0, kB1, vB0, vB1);
    }
#undef LOADSET

    // ---- block combine across the 4 k-splits ----
    if (islo) { mls[0][wid][c] = m; mls[1][wid][c] = lsum; }
    __syncthreads();

    float M = fmaxf(fmaxf(mls[0][0][c], mls[0][1][c]),
                    fmaxf(mls[0][2][c], mls[0][3][c]));
    float L = __builtin_amdgcn_exp2f(mls[0][0][c] - M) * mls[1][0][c]
            + __builtin_amdgcn_exp2f(mls[0][1][c] - M) * mls[1][1][c]
            + __builtin_amdgcn_exp2f(mls[0][2][c] - M) * mls[1][2][c]
            + __builtin_amdgcn_exp2f(mls[0][3][c] - M) * mls[1][3][c];
    float F = __builtin_amdgcn_exp2f(m - M);

    #pragma unroll
    for (int r = 0; r < 16; ++r) {
        int e = (r & 3) + 8 * (r >> 2) + 4 * hi;
        cacc[wid][e][c] = ctx[r] * F;
    }
    __syncthreads();

    // wave wid writes e-range [8*wid, 8*wid+8); lane handles 4 contiguous e
    const float rL = 1.0f / L;
    float o[4];
    #pragma unroll
    for (int i = 0; i < 4; ++i) {
        int e = 8 * wid + 4 * hi + i;
        o[i] = ((cacc[0][e][c] + cacc[1][e][c]) +
                (cacc[2][e][c] + cacc[3][e][c])) * rL;
    }
    const int b = bh >> 3, h = bh & 7;
    __bf16* dst = CTX + (((size_t)b * S_ + (q0 + c)) * H_ + h) * E_ + 8 * wid + 4 * hi;
    *reinterpret_cast<uint2*>(dst) = make_uint2(pack2(o[0], o[1]), pack2(o[2], o[3]));
}

// ---------------------------------------------------------------------------
// Outproj: out(8192x256 f32) = CTX(bf16) @ wo(f32).  grid (256,2), 4 waves,
// wave = one 32x32 output tile; wo gathered+converted on the fly (coalesced).
// ---------------------------------------------------------------------------
__global__ __launch_bounds__(256, 2) void outproj_kernel(
    const __bf16* __restrict__ CTX, const float* __restrict__ wo,
    float* __restrict__ out)
{
    const int tid = threadIdx.x;
    const int wid = tid >> 6, lane = tid & 63;
    const int c = lane & 31, hi = lane >> 5;
    const int row0 = blockIdx.x * 32;
    const int row = row0 + c;
    const int ct = blockIdx.y * 4 + wid;          // 0..7

    bf16x8 a[16];
    #pragma unroll
    for (int t = 0; t < 16; ++t)
        a[t] = *reinterpret_cast<const bf16x8*>(CTX + row * D_ + 16 * t + 8 * hi);

    const int col = ct * 32 + c;
    f32x16 acc = {};
    #pragma unroll
    for (int t = 0; t < 16; ++t) {
        const float* wp = wo + (16 * t + 8 * hi) * D_ + col;
        bf16x8 bb;
        #pragma unroll
        for (int i = 0; i < 8; ++i) bb[i] = (__bf16)wp[i * D_];
        acc = __builtin_amdgcn_mfma_f32_32x32x16_bf16(a[t], bb, acc, 0, 0, 0);
    }
    float* op = out + (size_t)row0 * D_ + ct * 32 + c;
    #pragma unroll
    for (int r = 0; r < 16; ++r) {
        int rr = (r & 3) + 8 * (r >> 2) + 4 * hi;
        op[rr * D_] = acc[r];
    }
}

// ---------------------------------------------------------------------------
extern "C" void kernel_launch(void* const* d_in, const int* in_sizes, int n_in,
                              void* d_out, int out_size, void* d_ws, size_t ws_size,
                              hipStream_t stream)
{
    (void)in_sizes; (void)n_in; (void)out_size; (void)ws_size;
    const float* x  = (const float*)d_in[0];
    const float* wq = (const float*)d_in[1];
    const float* wk = (const float*)d_in[2];
    const float* wv = (const float*)d_in[3];
    const float* wo = (const float*)d_in[4];
    float* out = (float*)d_out;

    char* ws = (char*)d_ws;
    __bf16* Qb  = (__bf16*)(ws);                  // 4 MB  [bh][S][E]
    __bf16* Kb  = (__bf16*)(ws + (4u  << 20));    // 4 MB  [bh][S][E]
    __bf16* VTb = (__bf16*)(ws + (8u  << 20));    // 4 MB  [bh][E][S]
    __bf16* CTX = (__bf16*)(ws + (12u << 20));    // 4 MB  [b][s][h][e]
    __bf16* wT  = (__bf16*)(ws + (12u << 20));    // 384 KB, dead before CTX written

    prep_kernel<<<768, 256, 0, stream>>>(wq, wk, wv, wT);
    qkv_kernel<<<dim3(256, 3), 256, 0, stream>>>(x, wT, Qb, Kb, VTb);
    attn_kernel<<<dim3(64, 32), 256, 0, stream>>>(Qb, Kb, VTb, CTX);
    outproj_kernel<<<dim3(256, 2), 256, 0, stream>>>(CTX, wo, out);
}

// Round 4
// 179.862 us; speedup vs baseline: 1.0229x; 1.0229x over previous
//
#include <hip/hip_runtime.h>
#include <hip/hip_bf16.h>
#include <cstdint>

typedef __bf16 bf16x8 __attribute__((ext_vector_type(8)));
typedef float  f32x16 __attribute__((ext_vector_type(16)));
typedef unsigned int uint2v __attribute__((ext_vector_type(2)));

#define B_ 4
#define S_ 2048
#define D_ 256
#define H_ 8
#define E_ 32

// d_model^-0.5 * log2(e) folded into Q so softmax uses exp2 directly
#define QSCALE (0.0625f * 1.44269504088896f)

__device__ inline unsigned short bfbits(float f) {
    return __builtin_bit_cast(unsigned short, (__bf16)f);
}
__device__ inline unsigned int pack2(float a, float b) {
    return (unsigned int)bfbits(a) | ((unsigned int)bfbits(b) << 16);
}

// ---------------------------------------------------------------------------
// Prep: wT[(op*8+h)*32+e][d] = w_op[h][d][e] (bf16, Q pre-scaled). 196608 elems.
// ---------------------------------------------------------------------------
__global__ __launch_bounds__(256) void prep_kernel(
    const float* __restrict__ wq, const float* __restrict__ wk,
    const float* __restrict__ wv, __bf16* __restrict__ wT)
{
    int idx = blockIdx.x * 256 + threadIdx.x;      // < 3*8*256*32 = 196608
    int op = idx >> 16;
    int h  = (idx >> 13) & 7;
    int d  = (idx >> 5) & 255;
    int e  = idx & 31;
    const float* w = (op == 0) ? wq : (op == 1) ? wk : wv;
    float v = w[(h * D_ + d) * E_ + e];
    if (op == 0) v *= QSCALE;
    wT[(((op * H_ + h) * E_ + e) << 8) | d] = (__bf16)v;
}

// ---------------------------------------------------------------------------
// QKV: x(8192x256 f32) @ wT^T -> Q,K [bh][S][E], V^T [bh][E][S]  (bf16)
// grid (256 row-tiles, 3 ops), 4 waves; each wave = 2 heads of its op.
// ---------------------------------------------------------------------------
__global__ __launch_bounds__(256, 2) void qkv_kernel(
    const float* __restrict__ x, const __bf16* __restrict__ wT,
    __bf16* __restrict__ Qb, __bf16* __restrict__ Kb, __bf16* __restrict__ VTb)
{
    const int tid = threadIdx.x;
    const int wid = tid >> 6, lane = tid & 63;
    const int c = lane & 31, hi = lane >> 5;
    const int row0 = blockIdx.x * 32;
    const int row = row0 + c;
    const int op = blockIdx.y;

    // A-fragments: step t covers d = 16t + 8*hi + (0..7)
    bf16x8 a[16];
    #pragma unroll
    for (int t = 0; t < 16; ++t) {
        const float4* px = reinterpret_cast<const float4*>(x + row * D_ + 16 * t + 8 * hi);
        float4 f0 = px[0], f1 = px[1];
        bf16x8 v;
        v[0]=(__bf16)f0.x; v[1]=(__bf16)f0.y; v[2]=(__bf16)f0.z; v[3]=(__bf16)f0.w;
        v[4]=(__bf16)f1.x; v[5]=(__bf16)f1.y; v[6]=(__bf16)f1.z; v[7]=(__bf16)f1.w;
        a[t] = v;
    }

    const int b  = row0 >> 11;
    const int s0 = row0 & (S_ - 1);

    for (int j = 0; j < 2; ++j) {
        const int h = wid * 2 + j;                 // head 0..7
        const int ct = op * 8 + h;
        const int col = ct * 32 + c;
        const __bf16* wp = wT + col * 256 + 8 * hi;

        f32x16 acc = {};
        #pragma unroll
        for (int t = 0; t < 16; ++t) {
            bf16x8 bb = *reinterpret_cast<const bf16x8*>(wp + 16 * t);
            acc = __builtin_amdgcn_mfma_f32_32x32x16_bf16(a[t], bb, acc, 0, 0, 0);
        }

        const int bh = b * H_ + h;
        if (op < 2) {
            __bf16* dst = (op == 0 ? Qb : Kb) + (size_t)bh * S_ * E_ + c;
            #pragma unroll
            for (int r = 0; r < 16; ++r) {
                int rr = (r & 3) + 8 * (r >> 2) + 4 * hi;
                dst[(size_t)(s0 + rr) * E_] = (__bf16)acc[r];
            }
        } else {
            __bf16* dst = VTb + ((size_t)bh * E_ + c) * S_ + s0;
            #pragma unroll
            for (int g4 = 0; g4 < 4; ++g4) {
                unsigned int lo  = pack2(acc[4*g4],   acc[4*g4+1]);
                unsigned int hi2 = pack2(acc[4*g4+2], acc[4*g4+3]);
                *reinterpret_cast<uint2*>(dst + 8 * g4 + 4 * hi) = make_uint2(lo, hi2);
            }
        }
    }
}

// ---------------------------------------------------------------------------
// Flash attention, 32x32 swapped form, block-level split-K.
// 1-D grid of 2048, XCD-swizzled so bh&7 == blockid&7: each XCD's L2 serves
// only 4 bh (1 MB K+V working set). Block = one 32-q tile, 4 waves; wave w
// handles k in [512w, 512w+512) with private online softmax, then the block
// combines partials through LDS.
// ---------------------------------------------------------------------------
__global__ __launch_bounds__(256, 8) void attn_kernel(
    const __bf16* __restrict__ Qb, const __bf16* __restrict__ Kb,
    const __bf16* __restrict__ VTb, __bf16* __restrict__ CTX)
{
    __shared__ float cacc[4][32][32];   // [wave][e][q] scaled partial ctx
    __shared__ float mls[2][4][32];     // m / lsum per wave per q

    const int tid = threadIdx.x;
    const int wid = tid >> 6, lane = tid & 63;
    const int c = lane & 31, hi = lane >> 5;

    // XCD-locality decode: assumes round-robin blockid->XCD (perf-only)
    const int i   = blockIdx.x;           // 0..2047
    const int xcd = i & 7, j = i >> 3;    // j: 0..255
    const int bh  = ((j & 3) << 3) | xcd; // bh&7 == xcd
    const int q0  = (j >> 2) * 32;        // qt: 0..63

    const bool islo = (hi == 0);
    const int kbeg = wid * 512;

    const __bf16* Qh    = Qb + (size_t)bh * S_ * E_;
    const __bf16* kbase = Kb + (size_t)bh * S_ * E_ + c * E_ + 8 * hi;
    const __bf16* vbase = VTb + (size_t)bh * E_ * S_ + c * S_ + 8 * hi;

    const bf16x8 qb0 = *reinterpret_cast<const bf16x8*>(Qh + (q0 + c) * E_ + 8 * hi);
    const bf16x8 qb1 = *reinterpret_cast<const bf16x8*>(Qh + (q0 + c) * E_ + 16 + 8 * hi);

    f32x16 ctx = {};
    float m = -1e30f, lsum = 0.f;

    bf16x8 kA0, kA1, vA0, vA1, kB0, kB1, vB0, vB1;

#define LOADSET(K0, K1, V0, V1, kt) do { \
    K0 = *reinterpret_cast<const bf16x8*>(kbase + (size_t)(kt) * E_);      \
    K1 = *reinterpret_cast<const bf16x8*>(kbase + (size_t)(kt) * E_ + 16); \
    V0 = *reinterpret_cast<const bf16x8*>(vbase + (kt));                   \
    V1 = *reinterpret_cast<const bf16x8*>(vbase + (kt) + 16); } while (0)

    auto xpartner = [&](float v) -> float {
        uint2v r = __builtin_amdgcn_permlane32_swap(
            __builtin_bit_cast(unsigned int, v),
            __builtin_bit_cast(unsigned int, v), false, false);
        return __builtin_bit_cast(float, islo ? r[1] : r[0]);
    };

    auto compute = [&](const bf16x8& K0, const bf16x8& K1,
                       const bf16x8& V0, const bf16x8& V1) {
        f32x16 sc = {};
        sc = __builtin_amdgcn_mfma_f32_32x32x16_bf16(K0, qb0, sc, 0, 0, 0);
        sc = __builtin_amdgcn_mfma_f32_32x32x16_bf16(K1, qb1, sc, 0, 0, 0);

        // per-lane max tree (partner swap deferred to the rare branch:
        // __all already spans all 64 lanes)
        float t0 = fmaxf(fmaxf(sc[0], sc[1]),  fmaxf(sc[2], sc[3]));
        float t1 = fmaxf(fmaxf(sc[4], sc[5]),  fmaxf(sc[6], sc[7]));
        float t2 = fmaxf(fmaxf(sc[8], sc[9]),  fmaxf(sc[10], sc[11]));
        float t3 = fmaxf(fmaxf(sc[12], sc[13]), fmaxf(sc[14], sc[15]));
        float t = fmaxf(fmaxf(t0, t1), fmaxf(t2, t3));

        if (!__all(t <= m + 8.0f)) {          // rescale (≈once per wave)
            t = fmaxf(t, xpartner(t));
            float mnew = fmaxf(m, t);
            float f = __builtin_amdgcn_exp2f(m - mnew);
            lsum *= f;
            #pragma unroll
            for (int i = 0; i < 16; ++i) ctx[i] *= f;
            m = mnew;
        }

        float p[16];
        #pragma unroll
        for (int i = 0; i < 16; ++i) p[i] = __builtin_amdgcn_exp2f(sc[i] - m);
        float s0 = (p[0] + p[1]) + (p[2] + p[3]);
        float s1 = (p[4] + p[5]) + (p[6] + p[7]);
        float s2 = (p[8] + p[9]) + (p[10] + p[11]);
        float s3 = (p[12] + p[13]) + (p[14] + p[15]);
        float psum = (s0 + s1) + (s2 + s3);
        psum += xpartner(psum);
        lsum += psum;

        // PV B-frag, k-half 0 (k 0..15)
        unsigned int c0 = pack2(p[0], p[1]), c1 = pack2(p[2], p[3]);
        unsigned int c2 = pack2(p[4], p[5]), c3 = pack2(p[6], p[7]);
        uint2v r02 = __builtin_amdgcn_permlane32_swap(c0, c2, false, false);
        uint2v r13 = __builtin_amdgcn_permlane32_swap(c1, c3, false, false);
        uint4 u0; u0.x = r02[0]; u0.y = r13[0]; u0.z = r02[1]; u0.w = r13[1];
        // k-half 1 (k 16..31)
        c0 = pack2(p[8], p[9]);   c1 = pack2(p[10], p[11]);
        c2 = pack2(p[12], p[13]); c3 = pack2(p[14], p[15]);
        r02 = __builtin_amdgcn_permlane32_swap(c0, c2, false, false);
        r13 = __builtin_amdgcn_permlane32_swap(c1, c3, false, false);
        uint4 u1; u1.x = r02[0]; u1.y = r13[0]; u1.z = r02[1]; u1.w = r13[1];

        __builtin_amdgcn_s_setprio(1);
        ctx = __builtin_amdgcn_mfma_f32_32x32x16_bf16(V0, __builtin_bit_cast(bf16x8, u0), ctx, 0, 0, 0);
        ctx = __builtin_amdgcn_mfma_f32_32x32x16_bf16(V1, __builtin_bit_cast(bf16x8, u1), ctx, 0, 0, 0);
        __builtin_amdgcn_s_setprio(0);
    };

    LOADSET(kA0, kA1, vA0, vA1, kbeg);
    for (int kt = kbeg; kt < kbeg + 512; kt += 64) {
        LOADSET(kB0, kB1, vB0, vB1, kt + 32);
        compute(kA0, kA1, vA0, vA1);
        int ktn = (kt + 64 < kbeg + 512) ? kt + 64 : kbeg;  // stay in-bounds
        LOADSET(kA0, kA1, vA0, vA1, ktn);
        compute(kB0, kB1, vB0, vB1);
    }
#undef LOADSET

    // ---- block combine across the 4 k-splits ----
    if (islo) { mls[0][wid][c] = m; mls[1][wid][c] = lsum; }
    __syncthreads();

    float M = fmaxf(fmaxf(mls[0][0][c], mls[0][1][c]),
                    fmaxf(mls[0][2][c], mls[0][3][c]));
    float L = __builtin_amdgcn_exp2f(mls[0][0][c] - M) * mls[1][0][c]
            + __builtin_amdgcn_exp2f(mls[0][1][c] - M) * mls[1][1][c]
            + __builtin_amdgcn_exp2f(mls[0][2][c] - M) * mls[1][2][c]
            + __builtin_amdgcn_exp2f(mls[0][3][c] - M) * mls[1][3][c];
    float F = __builtin_amdgcn_exp2f(m - M);

    #pragma unroll
    for (int r = 0; r < 16; ++r) {
        int e = (r & 3) + 8 * (r >> 2) + 4 * hi;
        cacc[wid][e][c] = ctx[r] * F;
    }
    __syncthreads();

    // wave wid writes e-range [8*wid, 8*wid+8); lane handles 4 contiguous e
    const float rL = 1.0f / L;
    float o[4];
    #pragma unroll
    for (int i2 = 0; i2 < 4; ++i2) {
        int e = 8 * wid + 4 * hi + i2;
        o[i2] = ((cacc[0][e][c] + cacc[1][e][c]) +
                 (cacc[2][e][c] + cacc[3][e][c])) * rL;
    }
    const int b = bh >> 3, h = bh & 7;
    __bf16* dst = CTX + (((size_t)b * S_ + (q0 + c)) * H_ + h) * E_ + 8 * wid + 4 * hi;
    *reinterpret_cast<uint2*>(dst) = make_uint2(pack2(o[0], o[1]), pack2(o[2], o[3]));
}

// ---------------------------------------------------------------------------
// Outproj: out(8192x256 f32) = CTX(bf16) @ wo(f32).  grid (256,2), 4 waves,
// wave = one 32x32 output tile; wo gathered+converted on the fly (coalesced).
// ---------------------------------------------------------------------------
__global__ __launch_bounds__(256, 2) void outproj_kernel(
    const __bf16* __restrict__ CTX, const float* __restrict__ wo,
    float* __restrict__ out)
{
    const int tid = threadIdx.x;
    const int wid = tid >> 6, lane = tid & 63;
    const int c = lane & 31, hi = lane >> 5;
    const int row0 = blockIdx.x * 32;
    const int row = row0 + c;
    const int ct = blockIdx.y * 4 + wid;          // 0..7

    bf16x8 a[16];
    #pragma unroll
    for (int t = 0; t < 16; ++t)
        a[t] = *reinterpret_cast<const bf16x8*>(CTX + row * D_ + 16 * t + 8 * hi);

    const int col = ct * 32 + c;
    f32x16 acc = {};
    #pragma unroll
    for (int t = 0; t < 16; ++t) {
        const float* wp = wo + (16 * t + 8 * hi) * D_ + col;
        bf16x8 bb;
        #pragma unroll
        for (int i = 0; i < 8; ++i) bb[i] = (__bf16)wp[i * D_];
        acc = __builtin_amdgcn_mfma_f32_32x32x16_bf16(a[t], bb, acc, 0, 0, 0);
    }
    float* op = out + (size_t)row0 * D_ + ct * 32 + c;
    #pragma unroll
    for (int r = 0; r < 16; ++r) {
        int rr = (r & 3) + 8 * (r >> 2) + 4 * hi;
        op[rr * D_] = acc[r];
    }
}

// ---------------------------------------------------------------------------
extern "C" void kernel_launch(void* const* d_in, const int* in_sizes, int n_in,
                              void* d_out, int out_size, void* d_ws, size_t ws_size,
                              hipStream_t stream)
{
    (void)in_sizes; (void)n_in; (void)out_size; (void)ws_size;
    const float* x  = (const float*)d_in[0];
    const float* wq = (const float*)d_in[1];
    const float* wk = (const float*)d_in[2];
    const float* wv = (const float*)d_in[3];
    const float* wo = (const float*)d_in[4];
    float* out = (float*)d_out;

    char* ws = (char*)d_ws;
    __bf16* Qb  = (__bf16*)(ws);                  // 4 MB  [bh][S][E]
    __bf16* Kb  = (__bf16*)(ws + (4u  << 20));    // 4 MB  [bh][S][E]
    __bf16* VTb = (__bf16*)(ws + (8u  << 20));    // 4 MB  [bh][E][S]
    __bf16* CTX = (__bf16*)(ws + (12u << 20));    // 4 MB  [b][s][h][e]
    __bf16* wT  = (__bf16*)(ws + (12u << 20));    // 384 KB, dead before CTX written

    prep_kernel<<<768, 256, 0, stream>>>(wq, wk, wv, wT);
    qkv_kernel<<<dim3(256, 3), 256, 0, stream>>>(x, wT, Qb, Kb, VTb);
    attn_kernel<<<2048, 256, 0, stream>>>(Qb, Kb, VTb, CTX);
    outproj_kernel<<<dim3(256, 2), 256, 0, stream>>>(CTX, wo, out);
}

// Round 5
// 92.885 us; speedup vs baseline: 1.9808x; 1.9364x over previous
//
#include <hip/hip_runtime.h>
#include <hip/hip_bf16.h>
#include <cstdint>

typedef __bf16 bf16x8 __attribute__((ext_vector_type(8)));
typedef float  f32x16 __attribute__((ext_vector_type(16)));
typedef unsigned int uint2v __attribute__((ext_vector_type(2)));

#define B_ 4
#define S_ 2048
#define D_ 256
#define H_ 8
#define E_ 32

// d_model^-0.5 * log2(e) folded into Q so softmax uses exp2 directly
#define QSCALE (0.0625f * 1.44269504088896f)

__device__ inline unsigned short bfbits(float f) {
    return __builtin_bit_cast(unsigned short, (__bf16)f);
}
__device__ inline unsigned int pack2(float a, float b) {
    return (unsigned int)bfbits(a) | ((unsigned int)bfbits(b) << 16);
}

// ---------------------------------------------------------------------------
// Prep: wT[(op*8+h)*32+e][d] = w_op[h][d][e] (bf16, Q pre-scaled). 196608 elems.
// ---------------------------------------------------------------------------
__global__ __launch_bounds__(256) void prep_kernel(
    const float* __restrict__ wq, const float* __restrict__ wk,
    const float* __restrict__ wv, __bf16* __restrict__ wT)
{
    int idx = blockIdx.x * 256 + threadIdx.x;      // < 3*8*256*32 = 196608
    int op = idx >> 16;
    int h  = (idx >> 13) & 7;
    int d  = (idx >> 5) & 255;
    int e  = idx & 31;
    const float* w = (op == 0) ? wq : (op == 1) ? wk : wv;
    float v = w[(h * D_ + d) * E_ + e];
    if (op == 0) v *= QSCALE;
    wT[(((op * H_ + h) * E_ + e) << 8) | d] = (__bf16)v;
}

// ---------------------------------------------------------------------------
// QKV: x(8192x256 f32) @ wT^T -> Q,K [bh][S][E], V^T [bh][E][S]  (bf16)
// grid (256 row-tiles, 3 ops), 4 waves; each wave = 2 heads of its op.
// ---------------------------------------------------------------------------
__global__ __launch_bounds__(256, 2) void qkv_kernel(
    const float* __restrict__ x, const __bf16* __restrict__ wT,
    __bf16* __restrict__ Qb, __bf16* __restrict__ Kb, __bf16* __restrict__ VTb)
{
    const int tid = threadIdx.x;
    const int wid = tid >> 6, lane = tid & 63;
    const int c = lane & 31, hi = lane >> 5;
    const int row0 = blockIdx.x * 32;
    const int row = row0 + c;
    const int op = blockIdx.y;

    // A-fragments: step t covers d = 16t + 8*hi + (0..7)
    bf16x8 a[16];
    #pragma unroll
    for (int t = 0; t < 16; ++t) {
        const float4* px = reinterpret_cast<const float4*>(x + row * D_ + 16 * t + 8 * hi);
        float4 f0 = px[0], f1 = px[1];
        bf16x8 v;
        v[0]=(__bf16)f0.x; v[1]=(__bf16)f0.y; v[2]=(__bf16)f0.z; v[3]=(__bf16)f0.w;
        v[4]=(__bf16)f1.x; v[5]=(__bf16)f1.y; v[6]=(__bf16)f1.z; v[7]=(__bf16)f1.w;
        a[t] = v;
    }

    const int b  = row0 >> 11;
    const int s0 = row0 & (S_ - 1);

    for (int j = 0; j < 2; ++j) {
        const int h = wid * 2 + j;                 // head 0..7
        const int ct = op * 8 + h;
        const int col = ct * 32 + c;
        const __bf16* wp = wT + col * 256 + 8 * hi;

        f32x16 acc = {};
        #pragma unroll
        for (int t = 0; t < 16; ++t) {
            bf16x8 bb = *reinterpret_cast<const bf16x8*>(wp + 16 * t);
            acc = __builtin_amdgcn_mfma_f32_32x32x16_bf16(a[t], bb, acc, 0, 0, 0);
        }

        const int bh = b * H_ + h;
        if (op < 2) {
            __bf16* dst = (op == 0 ? Qb : Kb) + (size_t)bh * S_ * E_ + c;
            #pragma unroll
            for (int r = 0; r < 16; ++r) {
                int rr = (r & 3) + 8 * (r >> 2) + 4 * hi;
                dst[(size_t)(s0 + rr) * E_] = (__bf16)acc[r];
            }
        } else {
            __bf16* dst = VTb + ((size_t)bh * E_ + c) * S_ + s0;
            #pragma unroll
            for (int g4 = 0; g4 < 4; ++g4) {
                unsigned int lo  = pack2(acc[4*g4],   acc[4*g4+1]);
                unsigned int hi2 = pack2(acc[4*g4+2], acc[4*g4+3]);
                *reinterpret_cast<uint2*>(dst + 8 * g4 + 4 * hi) = make_uint2(lo, hi2);
            }
        }
    }
}

// ---------------------------------------------------------------------------
// Flash attention, 32x32 swapped form, block-level split-K.
// 1-D grid of 2048, XCD-swizzled so bh&7 == blockid&7 (per-XCD K/V working
// set = 4 bh = 1 MB, fits the 4 MB L2). Block = one 32-q tile, 4 waves;
// wave w handles k in [512w, 512w+512) with private online softmax, then
// the block combines partials through LDS.
// launch_bounds (256,4): 128-VGPR budget -- (256,8) forced spills to
// scratch (round 3/4: 250 MB phantom WRITE_SIZE).
// ---------------------------------------------------------------------------
__global__ __launch_bounds__(256, 4) void attn_kernel(
    const __bf16* __restrict__ Qb, const __bf16* __restrict__ Kb,
    const __bf16* __restrict__ VTb, __bf16* __restrict__ CTX)
{
    __shared__ float cacc[4][32][32];   // [wave][e][q] scaled partial ctx
    __shared__ float mls[2][4][32];     // m / lsum per wave per q

    const int tid = threadIdx.x;
    const int wid = tid >> 6, lane = tid & 63;
    const int c = lane & 31, hi = lane >> 5;

    // XCD-locality decode: assumes round-robin blockid->XCD (perf-only)
    const int i   = blockIdx.x;           // 0..2047
    const int xcd = i & 7, j = i >> 3;    // j: 0..255
    const int bh  = ((j & 3) << 3) | xcd; // bh&7 == xcd
    const int q0  = (j >> 2) * 32;        // qt: 0..63

    const bool islo = (hi == 0);
    const int kbeg = wid * 512;

    const __bf16* Qh    = Qb + (size_t)bh * S_ * E_;
    const __bf16* kbase = Kb + (size_t)bh * S_ * E_ + c * E_ + 8 * hi;
    const __bf16* vbase = VTb + (size_t)bh * E_ * S_ + c * S_ + 8 * hi;

    const bf16x8 qb0 = *reinterpret_cast<const bf16x8*>(Qh + (q0 + c) * E_ + 8 * hi);
    const bf16x8 qb1 = *reinterpret_cast<const bf16x8*>(Qh + (q0 + c) * E_ + 16 + 8 * hi);

    f32x16 ctx = {};
    float m = -1e30f, lsum = 0.f;

    bf16x8 kA0, kA1, vA0, vA1, kB0, kB1, vB0, vB1;

#define LOADSET(K0, K1, V0, V1, kt) do { \
    K0 = *reinterpret_cast<const bf16x8*>(kbase + (size_t)(kt) * E_);      \
    K1 = *reinterpret_cast<const bf16x8*>(kbase + (size_t)(kt) * E_ + 16); \
    V0 = *reinterpret_cast<const bf16x8*>(vbase + (kt));                   \
    V1 = *reinterpret_cast<const bf16x8*>(vbase + (kt) + 16); } while (0)

    auto xpartner = [&](float v) -> float {
        uint2v r = __builtin_amdgcn_permlane32_swap(
            __builtin_bit_cast(unsigned int, v),
            __builtin_bit_cast(unsigned int, v), false, false);
        return __builtin_bit_cast(float, islo ? r[1] : r[0]);
    };

    auto compute = [&](const bf16x8& K0, const bf16x8& K1,
                       const bf16x8& V0, const bf16x8& V1) {
        f32x16 sc = {};
        sc = __builtin_amdgcn_mfma_f32_32x32x16_bf16(K0, qb0, sc, 0, 0, 0);
        sc = __builtin_amdgcn_mfma_f32_32x32x16_bf16(K1, qb1, sc, 0, 0, 0);

        // per-lane max tree (partner swap deferred to the rare branch:
        // __all already spans all 64 lanes)
        float t0 = fmaxf(fmaxf(sc[0], sc[1]),  fmaxf(sc[2], sc[3]));
        float t1 = fmaxf(fmaxf(sc[4], sc[5]),  fmaxf(sc[6], sc[7]));
        float t2 = fmaxf(fmaxf(sc[8], sc[9]),  fmaxf(sc[10], sc[11]));
        float t3 = fmaxf(fmaxf(sc[12], sc[13]), fmaxf(sc[14], sc[15]));
        float t = fmaxf(fmaxf(t0, t1), fmaxf(t2, t3));

        if (!__all(t <= m + 8.0f)) {          // rescale (≈once per wave)
            t = fmaxf(t, xpartner(t));
            float mnew = fmaxf(m, t);
            float f = __builtin_amdgcn_exp2f(m - mnew);
            lsum *= f;
            #pragma unroll
            for (int i = 0; i < 16; ++i) ctx[i] *= f;
            m = mnew;
        }

        // per-half: exp2 -> psum -> pack immediately (only 8 p-floats live)
        float psum = 0.f;
        uint4 u0, u1;
        #pragma unroll
        for (int h2 = 0; h2 < 2; ++h2) {
            float p[8];
            #pragma unroll
            for (int i = 0; i < 8; ++i)
                p[i] = __builtin_amdgcn_exp2f(sc[8 * h2 + i] - m);
            psum += ((p[0] + p[1]) + (p[2] + p[3])) +
                    ((p[4] + p[5]) + (p[6] + p[7]));
            unsigned int c0 = pack2(p[0], p[1]), c1 = pack2(p[2], p[3]);
            unsigned int c2 = pack2(p[4], p[5]), c3 = pack2(p[6], p[7]);
            uint2v r02 = __builtin_amdgcn_permlane32_swap(c0, c2, false, false);
            uint2v r13 = __builtin_amdgcn_permlane32_swap(c1, c3, false, false);
            uint4 u; u.x = r02[0]; u.y = r13[0]; u.z = r02[1]; u.w = r13[1];
            if (h2 == 0) u0 = u; else u1 = u;
        }
        psum += xpartner(psum);
        lsum += psum;

        __builtin_amdgcn_s_setprio(1);
        ctx = __builtin_amdgcn_mfma_f32_32x32x16_bf16(V0, __builtin_bit_cast(bf16x8, u0), ctx, 0, 0, 0);
        ctx = __builtin_amdgcn_mfma_f32_32x32x16_bf16(V1, __builtin_bit_cast(bf16x8, u1), ctx, 0, 0, 0);
        __builtin_amdgcn_s_setprio(0);
    };

    LOADSET(kA0, kA1, vA0, vA1, kbeg);
    for (int kt = kbeg; kt < kbeg + 512; kt += 64) {
        LOADSET(kB0, kB1, vB0, vB1, kt + 32);
        compute(kA0, kA1, vA0, vA1);
        int ktn = (kt + 64 < kbeg + 512) ? kt + 64 : kbeg;  // stay in-bounds
        LOADSET(kA0, kA1, vA0, vA1, ktn);
        compute(kB0, kB1, vB0, vB1);
    }
#undef LOADSET

    // ---- block combine across the 4 k-splits ----
    if (islo) { mls[0][wid][c] = m; mls[1][wid][c] = lsum; }
    __syncthreads();

    float M = fmaxf(fmaxf(mls[0][0][c], mls[0][1][c]),
                    fmaxf(mls[0][2][c], mls[0][3][c]));
    float L = __builtin_amdgcn_exp2f(mls[0][0][c] - M) * mls[1][0][c]
            + __builtin_amdgcn_exp2f(mls[0][1][c] - M) * mls[1][1][c]
            + __builtin_amdgcn_exp2f(mls[0][2][c] - M) * mls[1][2][c]
            + __builtin_amdgcn_exp2f(mls[0][3][c] - M) * mls[1][3][c];
    float F = __builtin_amdgcn_exp2f(m - M);

    #pragma unroll
    for (int r = 0; r < 16; ++r) {
        int e = (r & 3) + 8 * (r >> 2) + 4 * hi;
        cacc[wid][e][c] = ctx[r] * F;
    }
    __syncthreads();

    // wave wid writes e-range [8*wid, 8*wid+8); lane handles 4 contiguous e
    const float rL = 1.0f / L;
    float o[4];
    #pragma unroll
    for (int i2 = 0; i2 < 4; ++i2) {
        int e = 8 * wid + 4 * hi + i2;
        o[i2] = ((cacc[0][e][c] + cacc[1][e][c]) +
                 (cacc[2][e][c] + cacc[3][e][c])) * rL;
    }
    const int b = bh >> 3, h = bh & 7;
    __bf16* dst = CTX + (((size_t)b * S_ + (q0 + c)) * H_ + h) * E_ + 8 * wid + 4 * hi;
    *reinterpret_cast<uint2*>(dst) = make_uint2(pack2(o[0], o[1]), pack2(o[2], o[3]));
}

// ---------------------------------------------------------------------------
// Outproj: out(8192x256 f32) = CTX(bf16) @ wo(f32).  grid (256,2), 4 waves,
// wave = one 32x32 output tile; wo gathered+converted on the fly (coalesced).
// ---------------------------------------------------------------------------
__global__ __launch_bounds__(256, 2) void outproj_kernel(
    const __bf16* __restrict__ CTX, const float* __restrict__ wo,
    float* __restrict__ out)
{
    const int tid = threadIdx.x;
    const int wid = tid >> 6, lane = tid & 63;
    const int c = lane & 31, hi = lane >> 5;
    const int row0 = blockIdx.x * 32;
    const int row = row0 + c;
    const int ct = blockIdx.y * 4 + wid;          // 0..7

    bf16x8 a[16];
    #pragma unroll
    for (int t = 0; t < 16; ++t)
        a[t] = *reinterpret_cast<const bf16x8*>(CTX + row * D_ + 16 * t + 8 * hi);

    const int col = ct * 32 + c;
    f32x16 acc = {};
    #pragma unroll
    for (int t = 0; t < 16; ++t) {
        const float* wp = wo + (16 * t + 8 * hi) * D_ + col;
        bf16x8 bb;
        #pragma unroll
        for (int i = 0; i < 8; ++i) bb[i] = (__bf16)wp[i * D_];
        acc = __builtin_amdgcn_mfma_f32_32x32x16_bf16(a[t], bb, acc, 0, 0, 0);
    }
    float* op = out + (size_t)row0 * D_ + ct * 32 + c;
    #pragma unroll
    for (int r = 0; r < 16; ++r) {
        int rr = (r & 3) + 8 * (r >> 2) + 4 * hi;
        op[rr * D_] = acc[r];
    }
}

// ---------------------------------------------------------------------------
extern "C" void kernel_launch(void* const* d_in, const int* in_sizes, int n_in,
                              void* d_out, int out_size, void* d_ws, size_t ws_size,
                              hipStream_t stream)
{
    (void)in_sizes; (void)n_in; (void)out_size; (void)ws_size;
    const float* x  = (const float*)d_in[0];
    const float* wq = (const float*)d_in[1];
    const float* wk = (const float*)d_in[2];
    const float* wv = (const float*)d_in[3];
    const float* wo = (const float*)d_in[4];
    float* out = (float*)d_out;

    char* ws = (char*)d_ws;
    __bf16* Qb  = (__bf16*)(ws);                  // 4 MB  [bh][S][E]
    __bf16* Kb  = (__bf16*)(ws + (4u  << 20));    // 4 MB  [bh][S][E]
    __bf16* VTb = (__bf16*)(ws + (8u  << 20));    // 4 MB  [bh][E][S]
    __bf16* CTX = (__bf16*)(ws + (12u << 20));    // 4 MB  [b][s][h][e]
    __bf16* wT  = (__bf16*)(ws + (12u << 20));    // 384 KB, dead before CTX written

    prep_kernel<<<768, 256, 0, stream>>>(wq, wk, wv, wT);
    qkv_kernel<<<dim3(256, 3), 256, 0, stream>>>(x, wT, Qb, Kb, VTb);
    attn_kernel<<<2048, 256, 0, stream>>>(Qb, Kb, VTb, CTX);
    outproj_kernel<<<dim3(256, 2), 256, 0, stream>>>(CTX, wo, out);
}